// Round 1
// baseline (619.231 us; speedup 1.0000x reference)
//
#include <hip/hip_runtime.h>
#include <hip/hip_bf16.h>
#include <type_traits>

// Problem: B=2, T=2048, D_MODEL=2048, H=16, Hkv=4, hd=128.
// Outputs (fp32, concat): out[2,2048,2048] | k_roped[2,4,2048,128] | v[2,4,2048,128]
// Workspace need: 64 MB exactly (see layout in kernel_launch).

typedef short  short8 __attribute__((ext_vector_type(8)));
typedef float  f32x4  __attribute__((ext_vector_type(4)));

#define AS1(p) ((__attribute__((address_space(1))) void*)(p))
#define AS3(p) ((__attribute__((address_space(3))) void*)(p))

static __device__ inline short bf_bits(float f) {
    __hip_bfloat16 h = __float2bfloat16(f);
    return *reinterpret_cast<short*>(&h);
}

// ---------------- x fp32 -> bf16 ----------------
__global__ __launch_bounds__(256) void convert_x_kernel(
    const float* __restrict__ x, __hip_bfloat16* __restrict__ xb)
{
    int i = (blockIdx.x * 256 + threadIdx.x) * 4;
    float4 v = *reinterpret_cast<const float4*>(x + i);
    ushort4 o;
    o.x = (unsigned short)bf_bits(v.x);
    o.y = (unsigned short)bf_bits(v.y);
    o.z = (unsigned short)bf_bits(v.z);
    o.w = (unsigned short)bf_bits(v.w);
    *reinterpret_cast<ushort4*>(reinterpret_cast<unsigned short*>(xb) + i) = o;
}

// ---------------- W [K][N] fp32 -> WT [N][K] bf16 ----------------
__global__ void transpose_convert_kernel(
    const float* __restrict__ W, __hip_bfloat16* __restrict__ WT, int K, int N)
{
    __shared__ float tile[32][33];
    int n0 = blockIdx.x * 32, k0 = blockIdx.y * 32;
    int tx = threadIdx.x, ty = threadIdx.y;   // 32 x 8
#pragma unroll
    for (int i = 0; i < 32; i += 8)
        tile[ty + i][tx] = W[(size_t)(k0 + ty + i) * N + n0 + tx];
    __syncthreads();
#pragma unroll
    for (int i = 0; i < 32; i += 8)
        WT[(size_t)(n0 + ty + i) * K + k0 + tx] = __float2bfloat16(tile[tx][ty + i]);
}

// ---------------- GEMM: C[M][N] = A[M][K] * BT[N][K]^T (bf16 in, f32 acc) ----------------
// 128x128 tile, 4 waves (2x2 of 64x64), BK=32, global_load_lds width-16 staging.
template <typename CT>
__global__ __launch_bounds__(256) void gemm_bt_kernel(
    const __hip_bfloat16* __restrict__ A,
    const __hip_bfloat16* __restrict__ BT,
    CT* __restrict__ C, int M, int N, int K)
{
    const int tid  = threadIdx.x;
    const int w    = tid >> 6;
    const int lane = tid & 63;
    const int lo16 = lane & 15;
    const int grp  = lane >> 4;
    const int m0 = blockIdx.y << 7;
    const int n0 = blockIdx.x << 7;
    const int wm = (w >> 1) << 6;
    const int wn = (w & 1) << 6;

    __shared__ __hip_bfloat16 As[128 * 32];
    __shared__ __hip_bfloat16 Bs[128 * 32];

    f32x4 acc[4][4] = {};

    const int ch0 = w * 128 + lane;     // chunk ids for the two wave-loads
    const int ch1 = ch0 + 64;           // chunk c: row c>>2, col-octet c&3

    for (int k0 = 0; k0 < K; k0 += 32) {
        {
            const __hip_bfloat16* ga0 = A + (size_t)(m0 + (ch0 >> 2)) * K + k0 + (ch0 & 3) * 8;
            const __hip_bfloat16* ga1 = A + (size_t)(m0 + (ch1 >> 2)) * K + k0 + (ch1 & 3) * 8;
            const __hip_bfloat16* gb0 = BT + (size_t)(n0 + (ch0 >> 2)) * K + k0 + (ch0 & 3) * 8;
            const __hip_bfloat16* gb1 = BT + (size_t)(n0 + (ch1 >> 2)) * K + k0 + (ch1 & 3) * 8;
            __builtin_amdgcn_global_load_lds(AS1(ga0), AS3(As + w * 1024),       16, 0, 0);
            __builtin_amdgcn_global_load_lds(AS1(ga1), AS3(As + w * 1024 + 512), 16, 0, 0);
            __builtin_amdgcn_global_load_lds(AS1(gb0), AS3(Bs + w * 1024),       16, 0, 0);
            __builtin_amdgcn_global_load_lds(AS1(gb1), AS3(Bs + w * 1024 + 512), 16, 0, 0);
        }
        __syncthreads();   // drains vmcnt -> tile visible to all waves

        short8 af[4], bf[4];
#pragma unroll
        for (int mi = 0; mi < 4; ++mi)
            af[mi] = *reinterpret_cast<const short8*>(
                reinterpret_cast<const short*>(As) + (wm + mi * 16 + lo16) * 32 + grp * 8);
#pragma unroll
        for (int ni = 0; ni < 4; ++ni)
            bf[ni] = *reinterpret_cast<const short8*>(
                reinterpret_cast<const short*>(Bs) + (wn + ni * 16 + lo16) * 32 + grp * 8);
#pragma unroll
        for (int mi = 0; mi < 4; ++mi)
#pragma unroll
            for (int ni = 0; ni < 4; ++ni)
                acc[mi][ni] = __builtin_amdgcn_mfma_f32_16x16x32_bf16(
                    af[mi], bf[ni], acc[mi][ni], 0, 0, 0);
        __syncthreads();   // reads done before next-iter staging overwrites
    }

#pragma unroll
    for (int mi = 0; mi < 4; ++mi)
#pragma unroll
        for (int ni = 0; ni < 4; ++ni)
#pragma unroll
            for (int r = 0; r < 4; ++r) {
                int row = m0 + wm + mi * 16 + grp * 4 + r;   // D: row=(lane>>4)*4+reg
                int col = n0 + wn + ni * 16 + lo16;          //    col=lane&15
                float v = acc[mi][ni][r];
                if constexpr (std::is_same<CT, float>::value)
                    C[(size_t)row * N + col] = v;
                else
                    C[(size_t)row * N + col] = __float2bfloat16(v);
            }
}

// ---------------- RoPE on Q (16 heads) and K (4 heads) in qkv, k->d_out ----------------
__global__ __launch_bounds__(256) void rope_qk_kernel(
    __hip_bfloat16* __restrict__ qkv, float* __restrict__ outk)
{
    int idx = blockIdx.x * 256 + threadIdx.x;   // 4096*20*64
    int row = idx / 1280;
    int rem = idx - row * 1280;
    int hh = rem >> 6, d = rem & 63;
    int b = row >> 11, t = row & 2047;
    int col = (hh < 16) ? hh * 128 + d : 2048 + (hh - 16) * 128 + d;
    __hip_bfloat16* p = qkv + (size_t)row * 3072 + col;
    float x1 = __bfloat162float(p[0]);
    float x2 = __bfloat162float(p[64]);
    float invf = exp2f((float)d * -0.20762050593046f);  // 10000^(-d/64)
    float ang = (float)t * invf;
    float s, c;
    sincosf(ang, &s, &c);
    float o1 = x1 * c - x2 * s;
    float o2 = x2 * c + x1 * s;
    p[0]  = __float2bfloat16(o1);
    p[64] = __float2bfloat16(o2);
    if (hh >= 16) {
        int kh = hh - 16;
        float* ok = outk + (size_t)((b * 4 + kh) * 2048 + t) * 128 + d;
        ok[0]  = o1;
        ok[64] = o2;
    }
}

// ---------------- V: fp32 to d_out + bf16 V^T for attention ----------------
__global__ __launch_bounds__(256) void v_writeout_kernel(
    const __hip_bfloat16* __restrict__ qkv, float* __restrict__ outv,
    __hip_bfloat16* __restrict__ VT)
{
    int idx = blockIdx.x * 256 + threadIdx.x;   // 2^21: [b][kh][t][d]
    int d  = idx & 127;
    int t  = (idx >> 7) & 2047;
    int kh = (idx >> 18) & 3;
    int b  = idx >> 20;
    __hip_bfloat16 v = qkv[(size_t)(b * 2048 + t) * 3072 + 2560 + kh * 128 + d];
    outv[idx] = __bfloat162float(v);
    VT[(size_t)((b * 4 + kh) * 128 + d) * 2048 + t] = v;
}

// ---------------- Flash attention (causal, GQA) ----------------
// Block: 4 independent waves, each owns 16 q-rows. KVBLK=32.
__global__ __launch_bounds__(256) void attn_kernel(
    const __hip_bfloat16* __restrict__ qkv,
    const __hip_bfloat16* __restrict__ VT,
    __hip_bfloat16* __restrict__ outO)
{
    const int qblk = blockIdx.x;        // 0..31
    const int bh   = blockIdx.y;        // b*16 + h
    const int b = bh >> 4, h = bh & 15;
    const int kh = h >> 2;              // GQA: g = h / 4
    const int w = threadIdx.x >> 6;
    const int lane = threadIdx.x & 63;
    const int lo16 = lane & 15, grp = lane >> 4;
    const int qrow0 = qblk * 64 + w * 16;

    __shared__ alignas(16) short plds_all[4][16][40];  // per-wave P tile, padded
    short (*plds)[40] = plds_all[w];

    const short* qkvs = reinterpret_cast<const short*>(qkv);

    short8 qf[4];
    {
        const short* qp = qkvs + (size_t)(b * 2048 + qrow0 + lo16) * 3072 + h * 128 + grp * 8;
#pragma unroll
        for (int s = 0; s < 4; ++s) qf[s] = *reinterpret_cast<const short8*>(qp + s * 32);
    }

    f32x4 o[8] = {};
    float m[4], l[4];
#pragma unroll
    for (int r = 0; r < 4; ++r) { m[r] = -1e30f; l[r] = 0.f; }

    const float scale = 0.08838834764831845f;   // 1/sqrt(128)
    const size_t krowbase = (size_t)b * 2048 * 3072 + 2048 + kh * 128;
    const short* vtb = reinterpret_cast<const short*>(VT) + (size_t)(b * 4 + kh) * 128 * 2048;

    const int ntiles = (qrow0 + 15) / 32 + 1;   // per-wave causal bound
    for (int tile = 0; tile < ntiles; ++tile) {
        const int kb = tile * 32;
        f32x4 sg[2];
#pragma unroll
        for (int g = 0; g < 2; ++g) {
            const int key = kb + g * 16 + lo16;
            const short* kp = qkvs + krowbase + (size_t)key * 3072 + grp * 8;
            f32x4 acc = {};
#pragma unroll
            for (int ss = 0; ss < 4; ++ss) {
                short8 kf = *reinterpret_cast<const short8*>(kp + ss * 32);
                acc = __builtin_amdgcn_mfma_f32_16x16x32_bf16(qf[ss], kf, acc, 0, 0, 0);
            }
            sg[g] = acc;
        }
        // scale + causal mask.  D row = grp*4+r (q), col = lane&15 (key in group)
        const int qq0 = qrow0 + grp * 4;
#pragma unroll
        for (int g = 0; g < 2; ++g) {
            const int key = kb + g * 16 + lo16;
#pragma unroll
            for (int r = 0; r < 4; ++r) {
                float v = sg[g][r] * scale;
                sg[g][r] = (key <= qq0 + r) ? v : -1e30f;
            }
        }
        // row max across 32 keys: local pair max, then 16-lane butterfly
        float pm[4];
#pragma unroll
        for (int r = 0; r < 4; ++r) pm[r] = fmaxf(sg[0][r], sg[1][r]);
#pragma unroll
        for (int off = 1; off < 16; off <<= 1)
#pragma unroll
            for (int r = 0; r < 4; ++r) pm[r] = fmaxf(pm[r], __shfl_xor(pm[r], off));

        float c[4], rs[4];
#pragma unroll
        for (int r = 0; r < 4; ++r) {
            float mn = fmaxf(m[r], pm[r]);
            c[r] = __expf(m[r] - mn);
            m[r] = mn;
            rs[r] = 0.f;
        }
#pragma unroll
        for (int g = 0; g < 2; ++g)
#pragma unroll
            for (int r = 0; r < 4; ++r) {
                float p = __expf(sg[g][r] - m[r]);
                rs[r] += p;
                plds[grp * 4 + r][g * 16 + lo16] = bf_bits(p);
            }
#pragma unroll
        for (int off = 1; off < 16; off <<= 1)
#pragma unroll
            for (int r = 0; r < 4; ++r) rs[r] += __shfl_xor(rs[r], off);
#pragma unroll
        for (int r = 0; r < 4; ++r) l[r] = l[r] * c[r] + rs[r];
#pragma unroll
        for (int j = 0; j < 8; ++j)
#pragma unroll
            for (int r = 0; r < 4; ++r) o[j][r] *= c[r];

        // P back as A-fragment (row=lane&15, k=grp*8..+7), then PV
        short8 pf = *reinterpret_cast<const short8*>(&plds[lo16][grp * 8]);
#pragma unroll
        for (int j = 0; j < 8; ++j) {
            const short* vp = vtb + (size_t)(j * 16 + lo16) * 2048 + kb + grp * 8;
            short8 vf = *reinterpret_cast<const short8*>(vp);
            o[j] = __builtin_amdgcn_mfma_f32_16x16x32_bf16(pf, vf, o[j], 0, 0, 0);
        }
    }

#pragma unroll
    for (int j = 0; j < 8; ++j)
#pragma unroll
        for (int r = 0; r < 4; ++r) {
            float val = o[j][r] / l[r];
            outO[(size_t)(b * 2048 + qrow0 + grp * 4 + r) * 2048 + h * 128 + j * 16 + lo16] =
                __float2bfloat16(val);
        }
}

extern "C" void kernel_launch(void* const* d_in, const int* in_sizes, int n_in,
                              void* d_out, int out_size, void* d_ws, size_t ws_size,
                              hipStream_t stream)
{
    (void)in_sizes; (void)n_in; (void)out_size; (void)ws_size;
    const float* x  = (const float*)d_in[0];
    const float* Wq = (const float*)d_in[1];
    const float* Wk = (const float*)d_in[2];
    const float* Wv = (const float*)d_in[3];
    const float* Wo = (const float*)d_in[4];

    float* out0 = (float*)d_out;                  // [2,2048,2048]
    float* outk = out0 + 8388608;                 // [2,4,2048,128]
    float* outv = out0 + 10485760;                // [2,4,2048,128]

    // Workspace layout (bf16 elems), 64 MB total:
    __hip_bfloat16* wsb    = (__hip_bfloat16*)d_ws;
    __hip_bfloat16* xb     = wsb;                   //  8,388,608  [4096][2048]
    __hip_bfloat16* WqkvT  = xb + 8388608;          //  6,291,456  [3072][2048]
    __hip_bfloat16* WoT    = WqkvT + 6291456;       //  4,194,304  [2048][2048]
    __hip_bfloat16* qkv    = WoT + 4194304;         // 12,582,912  [4096][3072]
    __hip_bfloat16* VT     = qkv + 12582912;        //  2,097,152  [8][128][2048]
    __hip_bfloat16* attn_o = xb;                    // alias: xb dead after QKV GEMM

    convert_x_kernel<<<8192, 256, 0, stream>>>(x, xb);
    transpose_convert_kernel<<<dim3(64, 64), dim3(32, 8), 0, stream>>>(Wq, WqkvT, 2048, 2048);
    transpose_convert_kernel<<<dim3(16, 64), dim3(32, 8), 0, stream>>>(Wk, WqkvT + (size_t)2048 * 2048, 2048, 512);
    transpose_convert_kernel<<<dim3(16, 64), dim3(32, 8), 0, stream>>>(Wv, WqkvT + (size_t)2560 * 2048, 2048, 512);
    transpose_convert_kernel<<<dim3(64, 64), dim3(32, 8), 0, stream>>>(Wo, WoT, 2048, 2048);

    gemm_bt_kernel<__hip_bfloat16><<<dim3(24, 32), 256, 0, stream>>>(xb, WqkvT, qkv, 4096, 3072, 2048);

    rope_qk_kernel<<<20480, 256, 0, stream>>>(qkv, outk);
    v_writeout_kernel<<<8192, 256, 0, stream>>>(qkv, outv, VT);

    attn_kernel<<<dim3(32, 32), 256, 0, stream>>>(qkv, VT, attn_o);

    gemm_bt_kernel<float><<<dim3(16, 32), 256, 0, stream>>>(attn_o, WoT, out0, 4096, 2048, 2048);
}

// Round 2
// 288.365 us; speedup vs baseline: 2.1474x; 2.1474x over previous
//
#include <hip/hip_runtime.h>
#include <hip/hip_bf16.h>
#include <type_traits>

// Problem: B=2, T=2048, D_MODEL=2048, H=16, Hkv=4, hd=128.
// Outputs (fp32, concat): out[2,2048,2048] | k_roped[2,4,2048,128] | v[2,4,2048,128]

typedef short  short8 __attribute__((ext_vector_type(8)));
typedef float  f32x4  __attribute__((ext_vector_type(4)));

#define AS1(p) ((__attribute__((address_space(1))) void*)(p))
#define AS3(p) ((__attribute__((address_space(3))) void*)(p))

static __device__ inline short bf_bits(float f) {
    __hip_bfloat16 h = __float2bfloat16(f);
    return *reinterpret_cast<short*>(&h);
}

// ---------------- x fp32 -> bf16 ----------------
__global__ __launch_bounds__(256) void convert_x_kernel(
    const float* __restrict__ x, __hip_bfloat16* __restrict__ xb)
{
    int i = (blockIdx.x * 256 + threadIdx.x) * 4;
    float4 v = *reinterpret_cast<const float4*>(x + i);
    ushort4 o;
    o.x = (unsigned short)bf_bits(v.x);
    o.y = (unsigned short)bf_bits(v.y);
    o.z = (unsigned short)bf_bits(v.z);
    o.w = (unsigned short)bf_bits(v.w);
    *reinterpret_cast<ushort4*>(reinterpret_cast<unsigned short*>(xb) + i) = o;
}

// ---------------- W [K][N] fp32 -> WT [N][K] bf16 ----------------
__global__ void transpose_convert_kernel(
    const float* __restrict__ W, __hip_bfloat16* __restrict__ WT, int K, int N)
{
    __shared__ float tile[32][33];
    int n0 = blockIdx.x * 32, k0 = blockIdx.y * 32;
    int tx = threadIdx.x, ty = threadIdx.y;   // 32 x 8
#pragma unroll
    for (int i = 0; i < 32; i += 8)
        tile[ty + i][tx] = W[(size_t)(k0 + ty + i) * N + n0 + tx];
    __syncthreads();
#pragma unroll
    for (int i = 0; i < 32; i += 8)
        WT[(size_t)(n0 + ty + i) * K + k0 + tx] = __float2bfloat16(tile[tx][ty + i]);
}

// ---------------- GEMM: C[M][N] = A[M][K] * BT[N][K]^T (bf16 in, f32 acc) ----------------
template <typename CT>
__global__ __launch_bounds__(256) void gemm_bt_kernel(
    const __hip_bfloat16* __restrict__ A,
    const __hip_bfloat16* __restrict__ BT,
    CT* __restrict__ C, int M, int N, int K)
{
    const int tid  = threadIdx.x;
    const int w    = tid >> 6;
    const int lane = tid & 63;
    const int lo16 = lane & 15;
    const int grp  = lane >> 4;
    const int m0 = blockIdx.y << 7;
    const int n0 = blockIdx.x << 7;
    const int wm = (w >> 1) << 6;
    const int wn = (w & 1) << 6;

    __shared__ __hip_bfloat16 As[128 * 32];
    __shared__ __hip_bfloat16 Bs[128 * 32];

    f32x4 acc[4][4] = {};

    const int ch0 = w * 128 + lane;
    const int ch1 = ch0 + 64;

    for (int k0 = 0; k0 < K; k0 += 32) {
        {
            const __hip_bfloat16* ga0 = A + (size_t)(m0 + (ch0 >> 2)) * K + k0 + (ch0 & 3) * 8;
            const __hip_bfloat16* ga1 = A + (size_t)(m0 + (ch1 >> 2)) * K + k0 + (ch1 & 3) * 8;
            const __hip_bfloat16* gb0 = BT + (size_t)(n0 + (ch0 >> 2)) * K + k0 + (ch0 & 3) * 8;
            const __hip_bfloat16* gb1 = BT + (size_t)(n0 + (ch1 >> 2)) * K + k0 + (ch1 & 3) * 8;
            __builtin_amdgcn_global_load_lds(AS1(ga0), AS3(As + w * 1024),       16, 0, 0);
            __builtin_amdgcn_global_load_lds(AS1(ga1), AS3(As + w * 1024 + 512), 16, 0, 0);
            __builtin_amdgcn_global_load_lds(AS1(gb0), AS3(Bs + w * 1024),       16, 0, 0);
            __builtin_amdgcn_global_load_lds(AS1(gb1), AS3(Bs + w * 1024 + 512), 16, 0, 0);
        }
        __syncthreads();

        short8 af[4], bf[4];
#pragma unroll
        for (int mi = 0; mi < 4; ++mi)
            af[mi] = *reinterpret_cast<const short8*>(
                reinterpret_cast<const short*>(As) + (wm + mi * 16 + lo16) * 32 + grp * 8);
#pragma unroll
        for (int ni = 0; ni < 4; ++ni)
            bf[ni] = *reinterpret_cast<const short8*>(
                reinterpret_cast<const short*>(Bs) + (wn + ni * 16 + lo16) * 32 + grp * 8);
#pragma unroll
        for (int mi = 0; mi < 4; ++mi)
#pragma unroll
            for (int ni = 0; ni < 4; ++ni)
                acc[mi][ni] = __builtin_amdgcn_mfma_f32_16x16x32_bf16(
                    af[mi], bf[ni], acc[mi][ni], 0, 0, 0);
        __syncthreads();
    }

#pragma unroll
    for (int mi = 0; mi < 4; ++mi)
#pragma unroll
        for (int ni = 0; ni < 4; ++ni)
#pragma unroll
            for (int r = 0; r < 4; ++r) {
                int row = m0 + wm + mi * 16 + grp * 4 + r;
                int col = n0 + wn + ni * 16 + lo16;
                float v = acc[mi][ni][r];
                if constexpr (std::is_same<CT, float>::value)
                    C[(size_t)row * N + col] = v;
                else
                    C[(size_t)row * N + col] = __float2bfloat16(v);
            }
}

// ---------------- RoPE on Q (16 heads) and K (4 heads) in qkv, k->d_out ----------------
__global__ __launch_bounds__(256) void rope_qk_kernel(
    __hip_bfloat16* __restrict__ qkv, float* __restrict__ outk)
{
    int idx = blockIdx.x * 256 + threadIdx.x;   // 4096*20*64
    int row = idx / 1280;
    int rem = idx - row * 1280;
    int hh = rem >> 6, d = rem & 63;
    int b = row >> 11, t = row & 2047;
    int col = (hh < 16) ? hh * 128 + d : 2048 + (hh - 16) * 128 + d;
    __hip_bfloat16* p = qkv + (size_t)row * 3072 + col;
    float x1 = __bfloat162float(p[0]);
    float x2 = __bfloat162float(p[64]);
    float invf = exp2f((float)d * -0.20762050593046f);  // 10000^(-d/64)
    float ang = (float)t * invf;
    float s, c;
    sincosf(ang, &s, &c);
    float o1 = x1 * c - x2 * s;
    float o2 = x2 * c + x1 * s;
    p[0]  = __float2bfloat16(o1);
    p[64] = __float2bfloat16(o2);
    if (hh >= 16) {
        int kh = hh - 16;
        float* ok = outk + (size_t)((b * 4 + kh) * 2048 + t) * 128 + d;
        ok[0]  = o1;
        ok[64] = o2;
    }
}

// ---------------- V: fp32 to d_out + bf16 V^T for attention ----------------
__global__ __launch_bounds__(256) void v_writeout_kernel(
    const __hip_bfloat16* __restrict__ qkv, float* __restrict__ outv,
    __hip_bfloat16* __restrict__ VT)
{
    int idx = blockIdx.x * 256 + threadIdx.x;   // 2^21: [b][kh][t][d]
    int d  = idx & 127;
    int t  = (idx >> 7) & 2047;
    int kh = (idx >> 18) & 3;
    int b  = idx >> 20;
    __hip_bfloat16 v = qkv[(size_t)(b * 2048 + t) * 3072 + 2560 + kh * 128 + d];
    outv[idx] = __bfloat162float(v);
    VT[(size_t)((b * 4 + kh) * 128 + d) * 2048 + t] = v;
}

// ---------------- Flash attention v2 (causal, GQA) ----------------
// 512 threads = 8 waves, each wave owns 16 q-rows (q-block = 128). KVBLK = 64.
// K tile [64][128] and V^T tile [128][64] double-buffered in LDS via
// global_load_lds (async, issued before compute of current tile).
// XOR swizzle (col16 ^= row&7) applied via pre-swizzled global source; reads
// use the same XOR -> ~2-way max bank aliasing (free).
__global__ __launch_bounds__(512, 4) void attn_kernel(
    const __hip_bfloat16* __restrict__ qkv,
    const __hip_bfloat16* __restrict__ VT,
    __hip_bfloat16* __restrict__ outO)
{
    const int bh = blockIdx.x;          // b*16 + h
    const int b = bh >> 4, h = bh & 15;
    const int kh = h >> 2;
    const int yb = blockIdx.y;          // 0..15
    const int qblk = (yb < 8) ? yb : 23 - yb;   // pair heavy+light blocks per CU
    const int tid = threadIdx.x;
    const int w = tid >> 6;
    const int lane = tid & 63;
    const int lo16 = lane & 15, grp = lane >> 4;
    const int qrow0 = qblk * 128 + w * 16;

    __shared__ short Ks[2][64 * 128];   // 32 KB  [key][d]   (swizzled cols)
    __shared__ short Vs[2][128 * 64];   // 32 KB  [d][key]   (swizzled cols)
    __shared__ short Ps[8][16 * 64];    // 16 KB  per-wave P (swizzled cols)

    const short* qkvs = reinterpret_cast<const short*>(qkv);
    const size_t kbase = (size_t)b * 2048 * 3072 + 2048 + kh * 128;
    const short* vtb = reinterpret_cast<const short*>(VT) + (size_t)(b * 4 + kh) * 128 * 2048;
    short* pw = &Ps[w][0];

    // Q fragments (row = lo16, k-slice = grp*8 within each 32-chunk)
    short8 qf[4];
    {
        const short* qp = qkvs + (size_t)(b * 2048 + qrow0 + lo16) * 3072 + h * 128 + grp * 8;
#pragma unroll
        for (int s = 0; s < 4; ++s) qf[s] = *reinterpret_cast<const short8*>(qp + s * 32);
    }

    f32x4 o[8] = {};
    float m[4], l[4];
#pragma unroll
    for (int r = 0; r < 4; ++r) { m[r] = -1e30f; l[r] = 0.f; }

    const float scale = 0.08838834764831845f;   // 1/sqrt(128)
    const int ntiles = qblk * 2 + 2;

    // ---- staging: K chunks c=tid+i*512: row=c>>4, src col16=(c&15)^(row&7)
    //              V chunks c=tid+i*512: d=c>>3,  src col16=(c&7)^(d&7)
#define STAGE(buf, kb_)                                                              \
    {                                                                                \
        _Pragma("unroll")                                                            \
        for (int i = 0; i < 2; ++i) {                                                \
            int c = tid + i * 512;                                                   \
            int row = c >> 4, c16 = (c & 15) ^ (row & 7);                            \
            const short* src = qkvs + kbase + (size_t)((kb_) + row) * 3072 + c16 * 8;\
            __builtin_amdgcn_global_load_lds(AS1(src),                               \
                AS3(&Ks[buf][(w * 64 + i * 512) * 8]), 16, 0, 0);                    \
        }                                                                            \
        _Pragma("unroll")                                                            \
        for (int i = 0; i < 2; ++i) {                                                \
            int c = tid + i * 512;                                                   \
            int d = c >> 3, c16 = (c & 7) ^ (d & 7);                                 \
            const short* src = vtb + (size_t)d * 2048 + (kb_) + c16 * 8;             \
            __builtin_amdgcn_global_load_lds(AS1(src),                               \
                AS3(&Vs[buf][(w * 64 + i * 512) * 8]), 16, 0, 0);                    \
        }                                                                            \
    }

    STAGE(0, 0);
    __syncthreads();
    int cur = 0;

    for (int t = 0; t < ntiles; ++t) {
        const int kb = t * 64;
        if (t + 1 < ntiles) STAGE(cur ^ 1, kb + 64);

        // ---- QK^T: S[q=grp*4+r][key=kg*16+lo16]
        f32x4 sg[4];
        __builtin_amdgcn_s_setprio(1);
#pragma unroll
        for (int kg = 0; kg < 4; ++kg) {
            f32x4 acc = {};
#pragma unroll
            for (int ss = 0; ss < 4; ++ss) {
                short8 kf = *reinterpret_cast<const short8*>(
                    &Ks[cur][(kg * 16 + lo16) * 128 + (((ss * 4 + grp) ^ (lo16 & 7)) << 3)]);
                acc = __builtin_amdgcn_mfma_f32_16x16x32_bf16(qf[ss], kf, acc, 0, 0, 0);
            }
            sg[kg] = acc;
        }
        __builtin_amdgcn_s_setprio(0);

        // ---- scale + causal mask
        const int q0 = qrow0 + grp * 4;
#pragma unroll
        for (int kg = 0; kg < 4; ++kg) {
            const int key = kb + kg * 16 + lo16;
#pragma unroll
            for (int r = 0; r < 4; ++r) {
                float v = sg[kg][r] * scale;
                sg[kg][r] = (key <= q0 + r) ? v : -1e30f;
            }
        }

        // ---- row max over 64 keys: 4-way local + 16-lane butterfly
        float pm[4];
#pragma unroll
        for (int r = 0; r < 4; ++r)
            pm[r] = fmaxf(fmaxf(sg[0][r], sg[1][r]), fmaxf(sg[2][r], sg[3][r]));
#pragma unroll
        for (int off = 1; off < 16; off <<= 1)
#pragma unroll
            for (int r = 0; r < 4; ++r) pm[r] = fmaxf(pm[r], __shfl_xor(pm[r], off));

        float c[4], rs[4];
#pragma unroll
        for (int r = 0; r < 4; ++r) {
            float mn = fmaxf(m[r], pm[r]);
            c[r] = __expf(m[r] - mn);
            m[r] = mn;
            rs[r] = 0.f;
        }
        // ---- exp + P write (swizzled): row=grp*4+r, col=kg*16+lo16
#pragma unroll
        for (int kg = 0; kg < 4; ++kg)
#pragma unroll
            for (int r = 0; r < 4; ++r) {
                float p = __expf(sg[kg][r] - m[r]);
                rs[r] += p;
                int row = grp * 4 + r;
                int idx = row * 64 + (((kg * 2 + (lo16 >> 3)) ^ (row & 7)) << 3) + (lo16 & 7);
                pw[idx] = bf_bits(p);
            }
#pragma unroll
        for (int off = 1; off < 16; off <<= 1)
#pragma unroll
            for (int r = 0; r < 4; ++r) rs[r] += __shfl_xor(rs[r], off);
#pragma unroll
        for (int r = 0; r < 4; ++r) l[r] = l[r] * c[r] + rs[r];
#pragma unroll
        for (int j = 0; j < 8; ++j)
#pragma unroll
            for (int r = 0; r < 4; ++r) o[j][r] *= c[r];

        // ---- PV: A = P[q][key], B-frag = V^T rows (d), over 2 k-steps of 32 keys
        __builtin_amdgcn_s_setprio(1);
#pragma unroll
        for (int ks = 0; ks < 2; ++ks) {
            short8 pf = *reinterpret_cast<const short8*>(
                &pw[lo16 * 64 + (((ks * 4 + grp) ^ (lo16 & 7)) << 3)]);
#pragma unroll
            for (int j = 0; j < 8; ++j) {
                short8 vf = *reinterpret_cast<const short8*>(
                    &Vs[cur][(j * 16 + lo16) * 64 + (((ks * 4 + grp) ^ (lo16 & 7)) << 3)]);
                o[j] = __builtin_amdgcn_mfma_f32_16x16x32_bf16(pf, vf, o[j], 0, 0, 0);
            }
        }
        __builtin_amdgcn_s_setprio(0);

        __syncthreads();   // stage writes drained (vmcnt0) + all reads of cur done
        cur ^= 1;
    }
#undef STAGE

#pragma unroll
    for (int r = 0; r < 4; ++r) {
        float inv = 1.0f / l[r];
#pragma unroll
        for (int j = 0; j < 8; ++j) {
            outO[(size_t)(b * 2048 + qrow0 + grp * 4 + r) * 2048 + h * 128 + j * 16 + lo16] =
                __float2bfloat16(o[j][r] * inv);
        }
    }
}

extern "C" void kernel_launch(void* const* d_in, const int* in_sizes, int n_in,
                              void* d_out, int out_size, void* d_ws, size_t ws_size,
                              hipStream_t stream)
{
    (void)in_sizes; (void)n_in; (void)out_size; (void)ws_size;
    const float* x  = (const float*)d_in[0];
    const float* Wq = (const float*)d_in[1];
    const float* Wk = (const float*)d_in[2];
    const float* Wv = (const float*)d_in[3];
    const float* Wo = (const float*)d_in[4];

    float* out0 = (float*)d_out;                  // [2,2048,2048]
    float* outk = out0 + 8388608;                 // [2,4,2048,128]
    float* outv = out0 + 10485760;                // [2,4,2048,128]

    __hip_bfloat16* wsb    = (__hip_bfloat16*)d_ws;
    __hip_bfloat16* xb     = wsb;                   //  8,388,608  [4096][2048]
    __hip_bfloat16* WqkvT  = xb + 8388608;          //  6,291,456  [3072][2048]
    __hip_bfloat16* WoT    = WqkvT + 6291456;       //  4,194,304  [2048][2048]
    __hip_bfloat16* qkv    = WoT + 4194304;         // 12,582,912  [4096][3072]
    __hip_bfloat16* VT     = qkv + 12582912;        //  2,097,152  [8][128][2048]
    __hip_bfloat16* attn_o = xb;                    // alias: xb dead after QKV GEMM

    convert_x_kernel<<<8192, 256, 0, stream>>>(x, xb);
    transpose_convert_kernel<<<dim3(64, 64), dim3(32, 8), 0, stream>>>(Wq, WqkvT, 2048, 2048);
    transpose_convert_kernel<<<dim3(16, 64), dim3(32, 8), 0, stream>>>(Wk, WqkvT + (size_t)2048 * 2048, 2048, 512);
    transpose_convert_kernel<<<dim3(16, 64), dim3(32, 8), 0, stream>>>(Wv, WqkvT + (size_t)2560 * 2048, 2048, 512);
    transpose_convert_kernel<<<dim3(64, 64), dim3(32, 8), 0, stream>>>(Wo, WoT, 2048, 2048);

    gemm_bt_kernel<__hip_bfloat16><<<dim3(24, 32), 256, 0, stream>>>(xb, WqkvT, qkv, 4096, 3072, 2048);

    rope_qk_kernel<<<20480, 256, 0, stream>>>(qkv, outk);
    v_writeout_kernel<<<8192, 256, 0, stream>>>(qkv, outv, VT);

    attn_kernel<<<dim3(32, 16), 512, 0, stream>>>(qkv, VT, attn_o);

    gemm_bt_kernel<float><<<dim3(16, 32), 256, 0, stream>>>(attn_o, WoT, out0, 4096, 2048, 2048);
}

// Round 3
// 258.036 us; speedup vs baseline: 2.3998x; 1.1175x over previous
//
#include <hip/hip_runtime.h>
#include <hip/hip_bf16.h>
#include <type_traits>

// Problem: B=2, T=2048, D_MODEL=2048, H=16, Hkv=4, hd=128.
// Outputs (fp32, concat): out[2,2048,2048] | k_roped[2,4,2048,128] | v[2,4,2048,128]

typedef short  short8 __attribute__((ext_vector_type(8)));
typedef float  f32x4  __attribute__((ext_vector_type(4)));

#define AS1(p) ((__attribute__((address_space(1))) void*)(p))
#define AS3(p) ((__attribute__((address_space(3))) void*)(p))

static __device__ inline short bf_bits(float f) {
    __hip_bfloat16 h = __float2bfloat16(f);
    return *reinterpret_cast<short*>(&h);
}

// ---------------- x fp32 -> bf16 ----------------
__global__ __launch_bounds__(256) void convert_x_kernel(
    const float* __restrict__ x, __hip_bfloat16* __restrict__ xb)
{
    int i = (blockIdx.x * 256 + threadIdx.x) * 4;
    float4 v = *reinterpret_cast<const float4*>(x + i);
    ushort4 o;
    o.x = (unsigned short)bf_bits(v.x);
    o.y = (unsigned short)bf_bits(v.y);
    o.z = (unsigned short)bf_bits(v.z);
    o.w = (unsigned short)bf_bits(v.w);
    *reinterpret_cast<ushort4*>(reinterpret_cast<unsigned short*>(xb) + i) = o;
}

// ---------------- W [K][N] fp32 -> WT [N][K] bf16 ----------------
__global__ void transpose_convert_kernel(
    const float* __restrict__ W, __hip_bfloat16* __restrict__ WT, int K, int N)
{
    __shared__ float tile[32][33];
    int n0 = blockIdx.x * 32, k0 = blockIdx.y * 32;
    int tx = threadIdx.x, ty = threadIdx.y;   // 32 x 8
#pragma unroll
    for (int i = 0; i < 32; i += 8)
        tile[ty + i][tx] = W[(size_t)(k0 + ty + i) * N + n0 + tx];
    __syncthreads();
#pragma unroll
    for (int i = 0; i < 32; i += 8)
        WT[(size_t)(n0 + ty + i) * K + k0 + tx] = __float2bfloat16(tile[tx][ty + i]);
}

// ---------------- GEMM: C[M][N] = A[M][K] * BT[N][K]^T (bf16 in, f32 acc) ----------------
template <typename CT>
__global__ __launch_bounds__(256) void gemm_bt_kernel(
    const __hip_bfloat16* __restrict__ A,
    const __hip_bfloat16* __restrict__ BT,
    CT* __restrict__ C, int M, int N, int K)
{
    const int tid  = threadIdx.x;
    const int w    = tid >> 6;
    const int lane = tid & 63;
    const int lo16 = lane & 15;
    const int grp  = lane >> 4;
    const int m0 = blockIdx.y << 7;
    const int n0 = blockIdx.x << 7;
    const int wm = (w >> 1) << 6;
    const int wn = (w & 1) << 6;

    __shared__ __hip_bfloat16 As[128 * 32];
    __shared__ __hip_bfloat16 Bs[128 * 32];

    f32x4 acc[4][4] = {};

    const int ch0 = w * 128 + lane;
    const int ch1 = ch0 + 64;

    for (int k0 = 0; k0 < K; k0 += 32) {
        {
            const __hip_bfloat16* ga0 = A + (size_t)(m0 + (ch0 >> 2)) * K + k0 + (ch0 & 3) * 8;
            const __hip_bfloat16* ga1 = A + (size_t)(m0 + (ch1 >> 2)) * K + k0 + (ch1 & 3) * 8;
            const __hip_bfloat16* gb0 = BT + (size_t)(n0 + (ch0 >> 2)) * K + k0 + (ch0 & 3) * 8;
            const __hip_bfloat16* gb1 = BT + (size_t)(n0 + (ch1 >> 2)) * K + k0 + (ch1 & 3) * 8;
            __builtin_amdgcn_global_load_lds(AS1(ga0), AS3(As + w * 1024),       16, 0, 0);
            __builtin_amdgcn_global_load_lds(AS1(ga1), AS3(As + w * 1024 + 512), 16, 0, 0);
            __builtin_amdgcn_global_load_lds(AS1(gb0), AS3(Bs + w * 1024),       16, 0, 0);
            __builtin_amdgcn_global_load_lds(AS1(gb1), AS3(Bs + w * 1024 + 512), 16, 0, 0);
        }
        __syncthreads();

        short8 af[4], bf[4];
#pragma unroll
        for (int mi = 0; mi < 4; ++mi)
            af[mi] = *reinterpret_cast<const short8*>(
                reinterpret_cast<const short*>(As) + (wm + mi * 16 + lo16) * 32 + grp * 8);
#pragma unroll
        for (int ni = 0; ni < 4; ++ni)
            bf[ni] = *reinterpret_cast<const short8*>(
                reinterpret_cast<const short*>(Bs) + (wn + ni * 16 + lo16) * 32 + grp * 8);
#pragma unroll
        for (int mi = 0; mi < 4; ++mi)
#pragma unroll
            for (int ni = 0; ni < 4; ++ni)
                acc[mi][ni] = __builtin_amdgcn_mfma_f32_16x16x32_bf16(
                    af[mi], bf[ni], acc[mi][ni], 0, 0, 0);
        __syncthreads();
    }

#pragma unroll
    for (int mi = 0; mi < 4; ++mi)
#pragma unroll
        for (int ni = 0; ni < 4; ++ni)
#pragma unroll
            for (int r = 0; r < 4; ++r) {
                int row = m0 + wm + mi * 16 + grp * 4 + r;
                int col = n0 + wn + ni * 16 + lo16;
                float v = acc[mi][ni][r];
                if constexpr (std::is_same<CT, float>::value)
                    C[(size_t)row * N + col] = v;
                else
                    C[(size_t)row * N + col] = __float2bfloat16(v);
            }
}

// ---------------- RoPE on Q (16 heads) and K (4 heads) in qkv, k->d_out ----------------
__global__ __launch_bounds__(256) void rope_qk_kernel(
    __hip_bfloat16* __restrict__ qkv, float* __restrict__ outk)
{
    int idx = blockIdx.x * 256 + threadIdx.x;   // 4096*20*64
    int row = idx / 1280;
    int rem = idx - row * 1280;
    int hh = rem >> 6, d = rem & 63;
    int b = row >> 11, t = row & 2047;
    int col = (hh < 16) ? hh * 128 + d : 2048 + (hh - 16) * 128 + d;
    __hip_bfloat16* p = qkv + (size_t)row * 3072 + col;
    float x1 = __bfloat162float(p[0]);
    float x2 = __bfloat162float(p[64]);
    float invf = exp2f((float)d * -0.20762050593046f);  // 10000^(-d/64)
    float ang = (float)t * invf;
    float s, c;
    sincosf(ang, &s, &c);
    float o1 = x1 * c - x2 * s;
    float o2 = x2 * c + x1 * s;
    p[0]  = __float2bfloat16(o1);
    p[64] = __float2bfloat16(o2);
    if (hh >= 16) {
        int kh = hh - 16;
        float* ok = outk + (size_t)((b * 4 + kh) * 2048 + t) * 128 + d;
        ok[0]  = o1;
        ok[64] = o2;
    }
}

// ---------------- V: fp32 to d_out + bf16 V^T for attention ----------------
__global__ __launch_bounds__(256) void v_writeout_kernel(
    const __hip_bfloat16* __restrict__ qkv, float* __restrict__ outv,
    __hip_bfloat16* __restrict__ VT)
{
    int idx = blockIdx.x * 256 + threadIdx.x;   // 2^21: [b][kh][t][d]
    int d  = idx & 127;
    int t  = (idx >> 7) & 2047;
    int kh = (idx >> 18) & 3;
    int b  = idx >> 20;
    __hip_bfloat16 v = qkv[(size_t)(b * 2048 + t) * 3072 + 2560 + kh * 128 + d];
    outv[idx] = __bfloat162float(v);
    VT[(size_t)((b * 4 + kh) * 128 + d) * 2048 + t] = v;
}

// ---------------- Flash attention v3 (causal, GQA) ----------------
// 256 threads = 4 waves, each wave owns 32 q-rows (q-block = 128). KVBLK = 64.
// K/V fragments read once from LDS feed TWO row-block MFMAs (halves LDS BW
// per q-row vs v2). Row-sum via ones-column MFMA (no sum butterfly).
// exp2-domain softmax with defer-max (THR = 11.5 bits). Double-buffered
// K/V staged via global_load_lds with XOR-swizzled source.
__global__ __launch_bounds__(256, 2) void attn_kernel(
    const __hip_bfloat16* __restrict__ qkv,
    const __hip_bfloat16* __restrict__ VT,
    __hip_bfloat16* __restrict__ outO)
{
    const int bh = blockIdx.x;          // b*16 + h
    const int b = bh >> 4, h = bh & 15;
    const int kh = h >> 2;
    const int yb = blockIdx.y;          // 0..15
    const int qblk = (yb < 8) ? (15 - yb) : (yb - 8);   // LPT: heavy blocks first
    const int tid = threadIdx.x;
    const int w = tid >> 6;
    const int lane = tid & 63;
    const int lo16 = lane & 15, grp = lane >> 4;
    const int qrow0 = qblk * 128 + w * 32;

    __shared__ short Ks[2][64 * 128];   // 32 KB  [key][d]   (swizzled octets)
    __shared__ short Vs[2][128 * 64];   // 32 KB  [d][key]   (swizzled octets)
    __shared__ short Ps[4][32 * 64];    //  8 KB  per-wave P (swizzled octets)

    const short* qkvs = reinterpret_cast<const short*>(qkv);
    const size_t kbase = (size_t)b * 2048 * 3072 + 2048 + kh * 128;
    const short* vtb = reinterpret_cast<const short*>(VT) + (size_t)(b * 4 + kh) * 128 * 2048;
    short* pw = &Ps[w][0];

    // Q fragments: rows qrow0 + mi*16 + lo16, k-slice ss*32 + grp*8
    short8 qf[2][4];
#pragma unroll
    for (int mi = 0; mi < 2; ++mi) {
        const short* qp = qkvs + (size_t)(b * 2048 + qrow0 + mi * 16 + lo16) * 3072
                        + h * 128 + grp * 8;
#pragma unroll
        for (int ss = 0; ss < 4; ++ss)
            qf[mi][ss] = *reinterpret_cast<const short8*>(qp + ss * 32);
    }

    f32x4 o[2][8] = {};
    f32x4 lac[2] = {};
    float m[8];
#pragma unroll
    for (int r = 0; r < 8; ++r) m[r] = -1e30f;

    short8 ones;
#pragma unroll
    for (int j = 0; j < 8; ++j) ones[j] = (short)0x3F80;   // bf16 1.0

    const float scl2 = 0.12752749545902973f;   // (1/sqrt(128)) * log2(e)
    const int ntiles = qblk * 2 + 2;

#define STAGE(buf, kb_)                                                              \
    {                                                                                \
        _Pragma("unroll")                                                            \
        for (int i = 0; i < 4; ++i) {                                                \
            int c = tid + i * 256;                                                   \
            int row = c >> 4, c16 = (c & 15) ^ (row & 7);                            \
            const short* src = qkvs + kbase + (size_t)((kb_) + row) * 3072 + c16 * 8;\
            __builtin_amdgcn_global_load_lds(AS1(src),                               \
                AS3(&Ks[buf][(w * 64 + i * 256) * 8]), 16, 0, 0);                    \
        }                                                                            \
        _Pragma("unroll")                                                            \
        for (int i = 0; i < 4; ++i) {                                                \
            int c = tid + i * 256;                                                   \
            int d = c >> 3, c8 = (c & 7) ^ (d & 7);                                  \
            const short* src = vtb + (size_t)d * 2048 + (kb_) + c8 * 8;              \
            __builtin_amdgcn_global_load_lds(AS1(src),                               \
                AS3(&Vs[buf][(w * 64 + i * 256) * 8]), 16, 0, 0);                    \
        }                                                                            \
    }

    STAGE(0, 0);
    __syncthreads();
    int cur = 0;

    for (int t = 0; t < ntiles; ++t) {
        const int kb = t * 64;
        if (t + 1 < ntiles) STAGE(cur ^ 1, kb + 64);

        // ---- QK^T: S[mi][q=grp*4+r][key=kg*16+lo16], K-frag shared across mi
        f32x4 sg[2][4];
        __builtin_amdgcn_s_setprio(1);
#pragma unroll
        for (int kg = 0; kg < 4; ++kg) {
            f32x4 a0 = {}, a1 = {};
#pragma unroll
            for (int ss = 0; ss < 4; ++ss) {
                short8 kf = *reinterpret_cast<const short8*>(
                    &Ks[cur][(kg * 16 + lo16) * 128 + (((ss * 4 + grp) ^ (lo16 & 7)) << 3)]);
                a0 = __builtin_amdgcn_mfma_f32_16x16x32_bf16(qf[0][ss], kf, a0, 0, 0, 0);
                a1 = __builtin_amdgcn_mfma_f32_16x16x32_bf16(qf[1][ss], kf, a1, 0, 0, 0);
            }
            sg[0][kg] = a0; sg[1][kg] = a1;
        }
        __builtin_amdgcn_s_setprio(0);

        // ---- scale (log2 domain) + causal mask (only near diagonal)
        if (kb + 63 > qrow0) {
#pragma unroll
            for (int mi = 0; mi < 2; ++mi)
#pragma unroll
                for (int kg = 0; kg < 4; ++kg) {
                    const int key = kb + kg * 16 + lo16;
#pragma unroll
                    for (int r = 0; r < 4; ++r) {
                        float v = sg[mi][kg][r] * scl2;
                        sg[mi][kg][r] = (key <= qrow0 + mi * 16 + grp * 4 + r) ? v : -1e30f;
                    }
                }
        } else {
#pragma unroll
            for (int mi = 0; mi < 2; ++mi)
#pragma unroll
                for (int kg = 0; kg < 4; ++kg)
#pragma unroll
                    for (int r = 0; r < 4; ++r) sg[mi][kg][r] *= scl2;
        }

        // ---- row max over 64 keys: 4-way local + 16-lane butterfly
        float pm[8];
#pragma unroll
        for (int mi = 0; mi < 2; ++mi)
#pragma unroll
            for (int r = 0; r < 4; ++r)
                pm[mi * 4 + r] = fmaxf(fmaxf(sg[mi][0][r], sg[mi][1][r]),
                                       fmaxf(sg[mi][2][r], sg[mi][3][r]));
#pragma unroll
        for (int off = 1; off < 16; off <<= 1)
#pragma unroll
            for (int i = 0; i < 8; ++i) pm[i] = fmaxf(pm[i], __shfl_xor(pm[i], off));

        // ---- defer-max: rescale only when max grew materially (log2 dom, THR=11.5)
        bool ok = true;
#pragma unroll
        for (int i = 0; i < 8; ++i) ok = ok && (pm[i] <= m[i] + 11.5f);
        if (!__all(ok)) {
            float c[8];
#pragma unroll
            for (int i = 0; i < 8; ++i) {
                float mn = fmaxf(m[i], pm[i]);
                c[i] = __builtin_amdgcn_exp2f(m[i] - mn);
                m[i] = mn;
            }
#pragma unroll
            for (int mi = 0; mi < 2; ++mi) {
#pragma unroll
                for (int j = 0; j < 8; ++j)
#pragma unroll
                    for (int r = 0; r < 4; ++r) o[mi][j][r] *= c[mi * 4 + r];
#pragma unroll
                for (int r = 0; r < 4; ++r) lac[mi][r] *= c[mi * 4 + r];
            }
        }

        // ---- exp2 + P store (swizzled): row = mi*16 + grp*4 + r, col = kg*16+lo16
#pragma unroll
        for (int mi = 0; mi < 2; ++mi)
#pragma unroll
            for (int kg = 0; kg < 4; ++kg)
#pragma unroll
                for (int r = 0; r < 4; ++r) {
                    float p = __builtin_amdgcn_exp2f(sg[mi][kg][r] - m[mi * 4 + r]);
                    int row = mi * 16 + grp * 4 + r;
                    int idx = row * 64 + (((kg * 2 + (lo16 >> 3)) ^ (row & 7)) << 3) + (lo16 & 7);
                    pw[idx] = bf_bits(p);
                }

        // ---- PV + row-sum: V-frag shared across mi; l via ones-MFMA
        __builtin_amdgcn_s_setprio(1);
#pragma unroll
        for (int ks = 0; ks < 2; ++ks) {
            short8 pf0 = *reinterpret_cast<const short8*>(
                &pw[(0 * 16 + lo16) * 64 + (((ks * 4 + grp) ^ (lo16 & 7)) << 3)]);
            short8 pf1 = *reinterpret_cast<const short8*>(
                &pw[(1 * 16 + lo16) * 64 + (((ks * 4 + grp) ^ (lo16 & 7)) << 3)]);
            lac[0] = __builtin_amdgcn_mfma_f32_16x16x32_bf16(pf0, ones, lac[0], 0, 0, 0);
            lac[1] = __builtin_amdgcn_mfma_f32_16x16x32_bf16(pf1, ones, lac[1], 0, 0, 0);
#pragma unroll
            for (int j = 0; j < 8; ++j) {
                short8 vf = *reinterpret_cast<const short8*>(
                    &Vs[cur][(j * 16 + lo16) * 64 + (((ks * 4 + grp) ^ (lo16 & 7)) << 3)]);
                o[0][j] = __builtin_amdgcn_mfma_f32_16x16x32_bf16(pf0, vf, o[0][j], 0, 0, 0);
                o[1][j] = __builtin_amdgcn_mfma_f32_16x16x32_bf16(pf1, vf, o[1][j], 0, 0, 0);
            }
        }
        __builtin_amdgcn_s_setprio(0);

        __syncthreads();   // stage writes drained + all reads of cur done
        cur ^= 1;
    }
#undef STAGE

#pragma unroll
    for (int mi = 0; mi < 2; ++mi)
#pragma unroll
        for (int r = 0; r < 4; ++r) {
            float inv = 1.0f / lac[mi][r];
#pragma unroll
            for (int j = 0; j < 8; ++j) {
                outO[(size_t)(b * 2048 + qrow0 + mi * 16 + grp * 4 + r) * 2048
                     + h * 128 + j * 16 + lo16] = __float2bfloat16(o[mi][j][r] * inv);
            }
        }
}

extern "C" void kernel_launch(void* const* d_in, const int* in_sizes, int n_in,
                              void* d_out, int out_size, void* d_ws, size_t ws_size,
                              hipStream_t stream)
{
    (void)in_sizes; (void)n_in; (void)out_size; (void)ws_size;
    const float* x  = (const float*)d_in[0];
    const float* Wq = (const float*)d_in[1];
    const float* Wk = (const float*)d_in[2];
    const float* Wv = (const float*)d_in[3];
    const float* Wo = (const float*)d_in[4];

    float* out0 = (float*)d_out;                  // [2,2048,2048]
    float* outk = out0 + 8388608;                 // [2,4,2048,128]
    float* outv = out0 + 10485760;                // [2,4,2048,128]

    __hip_bfloat16* wsb    = (__hip_bfloat16*)d_ws;
    __hip_bfloat16* xb     = wsb;                   //  8,388,608  [4096][2048]
    __hip_bfloat16* WqkvT  = xb + 8388608;          //  6,291,456  [3072][2048]
    __hip_bfloat16* WoT    = WqkvT + 6291456;       //  4,194,304  [2048][2048]
    __hip_bfloat16* qkv    = WoT + 4194304;         // 12,582,912  [4096][3072]
    __hip_bfloat16* VT     = qkv + 12582912;        //  2,097,152  [8][128][2048]
    __hip_bfloat16* attn_o = xb;                    // alias: xb dead after QKV GEMM

    convert_x_kernel<<<8192, 256, 0, stream>>>(x, xb);
    transpose_convert_kernel<<<dim3(64, 64), dim3(32, 8), 0, stream>>>(Wq, WqkvT, 2048, 2048);
    transpose_convert_kernel<<<dim3(16, 64), dim3(32, 8), 0, stream>>>(Wk, WqkvT + (size_t)2048 * 2048, 2048, 512);
    transpose_convert_kernel<<<dim3(16, 64), dim3(32, 8), 0, stream>>>(Wv, WqkvT + (size_t)2560 * 2048, 2048, 512);
    transpose_convert_kernel<<<dim3(64, 64), dim3(32, 8), 0, stream>>>(Wo, WoT, 2048, 2048);

    gemm_bt_kernel<__hip_bfloat16><<<dim3(24, 32), 256, 0, stream>>>(xb, WqkvT, qkv, 4096, 3072, 2048);

    rope_qk_kernel<<<20480, 256, 0, stream>>>(qkv, outk);
    v_writeout_kernel<<<8192, 256, 0, stream>>>(qkv, outv, VT);

    attn_kernel<<<dim3(32, 16), 256, 0, stream>>>(qkv, VT, attn_o);

    gemm_bt_kernel<float><<<dim3(16, 32), 256, 0, stream>>>(attn_o, WoT, out0, 4096, 2048, 2048);
}